// Round 9
// baseline (54.454 us; speedup 1.0000x reference)
//
#include <hip/hip_runtime.h>
#include <math.h>
#include <float.h>

#define ROWS 1000000
#define NTHR 256
#define NBLK_L 3907                  // ceil(1e6 / 256)  -> one row per thread
#define NBLK_B 977                   // ceil(250000 float4 / 256)
#define NEG_BIG (-3.0e38f)

// ---- LDS offsets (floats) for the staged front weights ----
#define GWIH  0        // 1440
#define GBIH  1440     // 96
#define GWHH  1536     // 3072
#define GBHH  4608     // 96
#define OW1   4704     // 1024
#define OB1   5728     // 32
#define OW2   5760     // 1024
#define OB2   6784     // 32
#define ODEW  6816     // 160
#define ODEB  6976     // 32
#define FC5W  7008     // 768
#define FC5B  7776     // 24
#define FC6W  7800     // 768
#define FC6B  8568     // 24
#define RES   8592     // 3 chains x 1088: W1@0(512) B1@512(32) W2@544(512) B2@1056(32)
#define FXW   11856    // 3 x 88: W@0(80) B@80(5,pad8)
#define LNG   12120    // 15 (pad 16)
#define LNB   12136    // 15 (pad 16)
#define HID0  12152    // 32
#define WTOT  12184

// ---------------------------------------------------------------------------
// K0: front (1 block x 128). Stage ALL weights into LDS in one parallel shot,
// then run the (round-1-proven) chain math entirely out of LDS.
// ---------------------------------------------------------------------------
__global__ __launch_bounds__(128) void front_kernel(
    const int* __restrict__ x, const float* __restrict__ hidden, const int* __restrict__ pos,
    const float* __restrict__ loc_emb, const float* __restrict__ arr_emb,
    const float* __restrict__ dur_emb, const float* __restrict__ pos_emb,
    const float* __restrict__ f1rW1, const float* __restrict__ f1rb1,
    const float* __restrict__ f1rW2, const float* __restrict__ f1rb2,
    const float* __restrict__ f1W,   const float* __restrict__ f1b,
    const float* __restrict__ f2rW1, const float* __restrict__ f2rb1,
    const float* __restrict__ f2rW2, const float* __restrict__ f2rb2,
    const float* __restrict__ f2W,   const float* __restrict__ f2b,
    const float* __restrict__ f3rW1, const float* __restrict__ f3rb1,
    const float* __restrict__ f3rW2, const float* __restrict__ f3rb2,
    const float* __restrict__ f3W,   const float* __restrict__ f3b,
    const float* __restrict__ ln_g,  const float* __restrict__ ln_b,
    const float* __restrict__ ode_W, const float* __restrict__ ode_b,
    const float* __restrict__ oW1,   const float* __restrict__ ob1,
    const float* __restrict__ oW2,   const float* __restrict__ ob2,
    const float* __restrict__ fc5_W, const float* __restrict__ fc5_b,
    const float* __restrict__ fc6_W, const float* __restrict__ fc6_b,
    const float* __restrict__ gWih,  const float* __restrict__ gbih,
    const float* __restrict__ gWhh,  const float* __restrict__ gbhh,
    float* __restrict__ out, float* __restrict__ ws)
{
    __shared__ float w[WTOT];
    __shared__ float e[3][16], tr[3][16], h1[3][16];
    __shared__ float praw[15], pnorm[15];
    __shared__ float ode0[32], odt[32], hvec[32], hnew[32], pe[32];
    __shared__ float gi[96], gh[96];
    __shared__ float a5[24], a6[24];
    __shared__ float red[4];

    const int t = threadIdx.x;

    // ---- stage everything (independent loads, one round-trip) ----
#define ST4(ptr, OFF, N4) for (int i = t; i < (N4); i += 128) \
    ((float4*)(w + (OFF)))[i] = ((const float4*)(ptr))[i];
#define ST1(ptr, OFF, N) for (int i = t; i < (N); i += 128) \
    w[(OFF) + i] = (ptr)[i];

    ST4(gWih,  GWIH,  360)  ST4(gbih, GBIH, 24)
    ST4(gWhh,  GWHH,  768)  ST4(gbhh, GBHH, 24)
    ST4(oW1,   OW1,   256)  ST4(ob1,  OB1,  8)
    ST4(oW2,   OW2,   256)  ST4(ob2,  OB2,  8)
    ST4(ode_W, ODEW,  40)   ST4(ode_b,ODEB, 8)
    ST4(fc5_W, FC5W,  192)  ST4(fc5_b,FC5B, 6)
    ST4(fc6_W, FC6W,  192)  ST4(fc6_b,FC6B, 6)
    ST4(f1rW1, RES+0,        128) ST4(f1rb1, RES+512,        8)
    ST4(f1rW2, RES+544,      128) ST4(f1rb2, RES+1056,       8)
    ST4(f2rW1, RES+1088,     128) ST4(f2rb1, RES+1088+512,   8)
    ST4(f2rW2, RES+1088+544, 128) ST4(f2rb2, RES+1088+1056,  8)
    ST4(f3rW1, RES+2176,     128) ST4(f3rb1, RES+2176+512,   8)
    ST4(f3rW2, RES+2176+544, 128) ST4(f3rb2, RES+2176+1056,  8)
    ST4(f1W,   FXW+0,   20) ST1(f1b, FXW+80,      5)
    ST4(f2W,   FXW+88,  20) ST1(f2b, FXW+88+80,   5)
    ST4(f3W,   FXW+176, 20) ST1(f3b, FXW+176+80,  5)
    ST1(ln_g,  LNG, 15)     ST1(ln_b, LNB, 15)
    ST4(hidden, HID0, 8)

    if (t < 48) {
        int c = t >> 4, j = t & 15;
        const float* emb = (c == 0) ? (loc_emb + (size_t)x[0] * 16)
                         : (c == 1) ? (arr_emb + (size_t)x[1] * 16)
                                    : (dur_emb + (size_t)x[2] * 16);
        e[c][j] = emb[j];
    }
    if (t < 32) pe[t] = pos_emb[pos[0] * 32 + t];
    __syncthreads();

    // ---- two ResNet16 blocks per chain (LDS weights) ----
    for (int i = 0; i < 2; ++i) {
        if (t < 48) { int c = t >> 4, j = t & 15; tr[c][j] = fmaxf(e[c][j], 0.f); }
        __syncthreads();
        if (t < 48) {
            int c = t >> 4, j = t & 15;
            const float* W1 = w + RES + c * 1088 + i * 256 + j * 16;
            float a = w[RES + c * 1088 + 512 + i * 16 + j];
            #pragma unroll
            for (int k = 0; k < 16; ++k) a += W1[k] * tr[c][k];
            h1[c][j] = fmaxf(a, 0.f);
        }
        __syncthreads();
        if (t < 48) {
            int c = t >> 4, j = t & 15;
            const float* W2 = w + RES + c * 1088 + 544 + i * 256 + j * 16;
            float a = w[RES + c * 1088 + 1056 + i * 16 + j];
            #pragma unroll
            for (int k = 0; k < 16; ++k) a += W2[k] * h1[c][k];
            e[c][j] += 0.3f * a;
        }
        __syncthreads();
    }

    if (t < 15) {
        int c = t / 5, q = t % 5;
        const float* W = w + FXW + c * 88 + q * 16;
        float a = w[FXW + c * 88 + 80 + q];
        #pragma unroll
        for (int k = 0; k < 16; ++k) a += W[k] * e[c][k];
        praw[t] = a;
    }
    __syncthreads();

    if (t == 0) {
        float mu = 0.f;
        for (int k = 0; k < 15; ++k) mu += praw[k];
        mu *= (1.f / 15.f);
        float var = 0.f;
        for (int k = 0; k < 15; ++k) { float d = praw[k] - mu; var += d * d; }
        var *= (1.f / 15.f);
        red[0] = mu;
        red[1] = rsqrtf(var + 1e-5f);
    }
    __syncthreads();
    if (t < 15) pnorm[t] = (praw[t] - red[0]) * red[1] * w[LNG + t] + w[LNB + t];
    if (t < 32) {
        float a = w[ODEB + t];
        const float* W = w + ODEW + t * 5;
        #pragma unroll
        for (int k = 0; k < 5; ++k) a += W[k] * praw[10 + k];
        ode0[t] = a;
    }
    __syncthreads();
    if (t < 32) {
        float a = w[OB1 + t];
        const float* W = w + OW1 + t * 32;
        #pragma unroll
        for (int k = 0; k < 32; ++k) a += W[k] * fmaxf(ode0[k], 0.f);
        odt[t] = fmaxf(a, 0.f);
    }
    __syncthreads();
    if (t < 32) {
        float a = w[OB2 + t];
        const float* W = w + OW2 + t * 32;
        #pragma unroll
        for (int k = 0; k < 32; ++k) a += W[k] * odt[k];
        hvec[t] = w[HID0 + t] + ode0[t] + 0.3f * a;
    }
    __syncthreads();
    if (t < 96) {
        float a = w[GBIH + t];
        const float* W = w + GWIH + t * 15;
        #pragma unroll
        for (int k = 0; k < 15; ++k) a += W[k] * pnorm[k];
        gi[t] = a;
        float c2 = w[GBHH + t];
        const float* V = w + GWHH + t * 32;
        #pragma unroll
        for (int k = 0; k < 32; ++k) c2 += V[k] * hvec[k];
        gh[t] = c2;
    }
    __syncthreads();
    if (t < 32) {
        float r = 1.f / (1.f + expf(-(gi[t] + gh[t])));
        float z = 1.f / (1.f + expf(-(gi[32 + t] + gh[32 + t])));
        float n = tanhf(gi[64 + t] + r * gh[64 + t]);
        float hn = (1.f - z) * n + z * hvec[t];
        hnew[t] = hn;
        ws[t] = hn;
        out[ROWS + 48 + t] = hn;
    }
    __syncthreads();
    if (t < 24) {
        float a = w[FC5B + t];
        const float* W = w + FC5W + t * 32;
        #pragma unroll
        for (int k = 0; k < 32; ++k) a += W[k] * (hnew[k] + pe[k]);
        a5[t] = a;
        float b = w[FC6B + t];
        const float* V = w + FC6W + t * 32;
        #pragma unroll
        for (int k = 0; k < 32; ++k) b += V[k] * hnew[k];
        a6[t] = b;
    }
    __syncthreads();
    if (t == 0) {
        float m = -INFINITY;
        for (int k = 0; k < 24; ++k) m = fmaxf(m, a5[k]);
        float s = 0.f;
        for (int k = 0; k < 24; ++k) s += expf(a5[k] - m);
        red[2] = m + logf(s);
        m = -INFINITY;
        for (int k = 0; k < 24; ++k) m = fmaxf(m, a6[k]);
        s = 0.f;
        for (int k = 0; k < 24; ++k) s += expf(a6[k] - m);
        red[3] = m + logf(s);
    }
    __syncthreads();
    if (t < 24) {
        out[ROWS + t]      = a5[t] - red[2];
        out[ROWS + 24 + t] = a6[t] - red[3];
    }
}

// ---------------------------------------------------------------------------
// K1: one row per thread (round-6 PASSING version, byte-identical).
// ---------------------------------------------------------------------------
__global__ __launch_bounds__(NTHR) void logits_kernel(
    const float* __restrict__ W, const float* __restrict__ b,
    const float* __restrict__ ws_h, float* __restrict__ out,
    float2* __restrict__ partials)
{
    __shared__ float hs[32];
    if (threadIdx.x < 32) hs[threadIdx.x] = ws_h[threadIdx.x];
    __syncthreads();

    const int t = threadIdx.x;
    const int r = blockIdx.x * NTHR + t;

    float m = NEG_BIG, s = 0.f;
    if (r < ROWS) {
        const float4* W4 = (const float4*)W;
        float4 w[8];
        #pragma unroll
        for (int j = 0; j < 8; ++j) w[j] = W4[(size_t)r * 8 + j];
        float acc = b[r];
        #pragma unroll
        for (int j = 0; j < 8; ++j)
            acc += w[j].x * hs[4*j] + w[j].y * hs[4*j+1]
                 + w[j].z * hs[4*j+2] + w[j].w * hs[4*j+3];
        out[r] = acc;
        m = acc; s = 1.f;
    }

    __shared__ float sm[NTHR], ss[NTHR];
    sm[t] = m; ss[t] = s;
    __syncthreads();
    for (int off = NTHR / 2; off > 0; off >>= 1) {
        if (t < off) {
            float m2 = sm[t + off], s2 = ss[t + off];
            float M  = fmaxf(sm[t], m2);
            ss[t] = ss[t] * __expf(sm[t] - M) + s2 * __expf(m2 - M);
            sm[t] = M;
        }
        __syncthreads();
    }
    if (t == 0) partials[blockIdx.x] = make_float2(sm[0], ss[0]);
}

// ---------------------------------------------------------------------------
// K2: redundant partial reduce + fused subtract (round-6, byte-identical).
// ---------------------------------------------------------------------------
__global__ __launch_bounds__(256) void finalize_kernel(
    const float2* __restrict__ partials, float* __restrict__ out)
{
    __shared__ float sm[256], ss[256];
    __shared__ float lse_sh;
    const int t = threadIdx.x;

    float fm = NEG_BIG, fs = 0.f;
    for (int i = t; i < NBLK_L; i += 256) {
        float2 p2 = partials[i];
        float M = fmaxf(fm, p2.x);
        fs = fs * __expf(fm - M) + p2.y * __expf(p2.x - M);
        fm = M;
    }
    sm[t] = fm; ss[t] = fs;
    __syncthreads();
    for (int off = 128; off > 0; off >>= 1) {
        if (t < off) {
            float m2 = sm[t + off], s2 = ss[t + off];
            float M  = fmaxf(sm[t], m2);
            ss[t] = ss[t] * __expf(sm[t] - M) + s2 * __expf(m2 - M);
            sm[t] = M;
        }
        __syncthreads();
    }
    if (t == 0) lse_sh = sm[0] + logf(ss[0]);
    __syncthreads();
    const float lse = lse_sh;

    const int idx = blockIdx.x * 256 + t;
    if (idx < ROWS / 4) {
        float4* o4 = (float4*)out;
        float4 v = o4[idx];
        v.x -= lse; v.y -= lse; v.z -= lse; v.w -= lse;
        o4[idx] = v;
    }
}

extern "C" void kernel_launch(void* const* d_in, const int* in_sizes, int n_in,
                              void* d_out, int out_size, void* d_ws, size_t ws_size,
                              hipStream_t stream) {
    const int*   x       = (const int*)  d_in[0];
    const float* hidden  = (const float*)d_in[1];
    const int*   pos     = (const int*)  d_in[2];
    const float* loc_emb = (const float*)d_in[3];
    const float* arr_emb = (const float*)d_in[4];
    const float* dur_emb = (const float*)d_in[5];
    const float* pos_emb = (const float*)d_in[6];
    const float* f1rW1 = (const float*)d_in[7];
    const float* f1rb1 = (const float*)d_in[8];
    const float* f1rW2 = (const float*)d_in[9];
    const float* f1rb2 = (const float*)d_in[10];
    const float* f1W   = (const float*)d_in[11];
    const float* f1b   = (const float*)d_in[12];
    const float* f2rW1 = (const float*)d_in[13];
    const float* f2rb1 = (const float*)d_in[14];
    const float* f2rW2 = (const float*)d_in[15];
    const float* f2rb2 = (const float*)d_in[16];
    const float* f2W   = (const float*)d_in[17];
    const float* f2b   = (const float*)d_in[18];
    const float* f3rW1 = (const float*)d_in[19];
    const float* f3rb1 = (const float*)d_in[20];
    const float* f3rW2 = (const float*)d_in[21];
    const float* f3rb2 = (const float*)d_in[22];
    const float* f3W   = (const float*)d_in[23];
    const float* f3b   = (const float*)d_in[24];
    const float* ln_g  = (const float*)d_in[25];
    const float* ln_b  = (const float*)d_in[26];
    const float* ode_W = (const float*)d_in[27];
    const float* ode_b = (const float*)d_in[28];
    const float* oW1   = (const float*)d_in[29];
    const float* ob1   = (const float*)d_in[30];
    const float* oW2   = (const float*)d_in[31];
    const float* ob2   = (const float*)d_in[32];
    const float* fc4_W = (const float*)d_in[33];
    const float* fc4_b = (const float*)d_in[34];
    const float* fc5_W = (const float*)d_in[35];
    const float* fc5_b = (const float*)d_in[36];
    const float* fc6_W = (const float*)d_in[37];
    const float* fc6_b = (const float*)d_in[38];
    const float* gWih  = (const float*)d_in[39];
    const float* gbih  = (const float*)d_in[40];
    const float* gWhh  = (const float*)d_in[41];
    const float* gbhh  = (const float*)d_in[42];

    float* out = (float*)d_out;
    float* wsf = (float*)d_ws;
    // ws layout: [0:32) h_new ; [64 : 64+2*NBLK_L) partials (float2-aligned)
    float*  ws_h        = wsf;
    float2* ws_partials = (float2*)(wsf + 64);

    front_kernel<<<1, 128, 0, stream>>>(
        x, hidden, pos, loc_emb, arr_emb, dur_emb, pos_emb,
        f1rW1, f1rb1, f1rW2, f1rb2, f1W, f1b,
        f2rW1, f2rb1, f2rW2, f2rb2, f2W, f2b,
        f3rW1, f3rb1, f3rW2, f3rb2, f3W, f3b,
        ln_g, ln_b, ode_W, ode_b, oW1, ob1, oW2, ob2,
        fc5_W, fc5_b, fc6_W, fc6_b, gWih, gbih, gWhh, gbhh,
        out, ws_h);

    logits_kernel<<<NBLK_L, NTHR, 0, stream>>>(
        fc4_W, fc4_b, ws_h, out, ws_partials);

    finalize_kernel<<<NBLK_B, 256, 0, stream>>>(ws_partials, out);
}